// Round 3
// baseline (730.521 us; speedup 1.0000x reference)
//
#include <hip/hip_runtime.h>
#include <stdint.h>

#define S_DIM 2
#define B_DIM 2048
#define D_DIM 1024
#define H_DIM 2048
#define E_DIM 8
#define O_DIM 1024
#define NTOK 4096            // S*B
#define CAP 12288            // pair capacity (normal total = 8192)

typedef __attribute__((ext_vector_type(8))) short bf16x8;
typedef __attribute__((ext_vector_type(4))) float f32x4;

__device__ __forceinline__ unsigned short f2bf(float f) {
    union { float f; uint32_t i; } c; c.f = f;
    uint32_t r = c.i + 0x7FFFu + ((c.i >> 16) & 1u);
    return (unsigned short)(r >> 16);
}
__device__ __forceinline__ uint32_t pack2(float a, float b) {
    return (uint32_t)f2bf(a) | ((uint32_t)f2bf(b) << 16);
}
// read 8 fp32, round to bf16, write 16B
__device__ __forceinline__ void stage8(const float* __restrict__ src,
                                       unsigned short* __restrict__ dst) {
    float4 f0 = *(const float4*)src;
    float4 f1 = *(const float4*)(src + 4);
    int4 v;
    v.x = (int)pack2(f0.x, f0.y);
    v.y = (int)pack2(f0.z, f0.w);
    v.z = (int)pack2(f1.x, f1.y);
    v.w = (int)pack2(f1.z, f1.w);
    *(int4*)dst = v;
}

// async global(16B)->LDS. Global addr is per-lane; LDS dest must be wave-uniform
// (HW adds lane*16).
__device__ __forceinline__ void glds16(const unsigned short* g, unsigned short* l) {
    __builtin_amdgcn_global_load_lds(
        (__attribute__((address_space(1))) void*)g,
        (__attribute__((address_space(3))) void*)l,
        16, 0, 0);
}

// ---------------------------------------------------------------------------
// Kernel 0: fp32 -> bf16 bulk convert. 8 elems / thread.
// ---------------------------------------------------------------------------
__global__ __launch_bounds__(256) void convert_kernel(
    const float* __restrict__ src, unsigned short* __restrict__ dst, int n8)
{
    int i = blockIdx.x * blockDim.x + threadIdx.x;
    if (i < n8) stage8(src + (size_t)i * 8, dst + (size_t)i * 8);
}

// ---------------------------------------------------------------------------
// Kernel 1: gating (pure fp32 — must reproduce reference top-2 selection).
// One wave per token. Also emits xs in bf16 (it reads all of xs anyway).
// ---------------------------------------------------------------------------
__global__ __launch_bounds__(256) void gating_kernel(
    const float* __restrict__ xs,
    const float* __restrict__ Wg,
    const float* __restrict__ bvec,
    float* __restrict__ probs_out,
    int* __restrict__ counts,
    int* __restrict__ sel_cnt,
    int* __restrict__ sel_e,
    float* __restrict__ sel_g,
    unsigned short* __restrict__ xs_bf)
{
    const int wave = threadIdx.x >> 6;
    const int lane = threadIdx.x & 63;
    const int t = blockIdx.x * 4 + wave;
    const float* x = xs + (size_t)t * D_DIM;

    float acc[8];
#pragma unroll
    for (int e = 0; e < 8; ++e) acc[e] = 0.f;

#pragma unroll
    for (int i = 0; i < D_DIM / 64; ++i) {
        int d = i * 64 + lane;
        float xv = x[d];
        xs_bf[(size_t)t * D_DIM + d] = f2bf(xv);
        float4 w0 = *(const float4*)(Wg + (size_t)d * 8);
        float4 w1 = *(const float4*)(Wg + (size_t)d * 8 + 4);
        acc[0] += xv * w0.x; acc[1] += xv * w0.y;
        acc[2] += xv * w0.z; acc[3] += xv * w0.w;
        acc[4] += xv * w1.x; acc[5] += xv * w1.y;
        acc[6] += xv * w1.z; acc[7] += xv * w1.w;
    }
#pragma unroll
    for (int off = 32; off > 0; off >>= 1) {
#pragma unroll
        for (int e = 0; e < 8; ++e)
            acc[e] += __shfl_down(acc[e], off);
    }

    if (lane == 0) {
        float Hg[8];
#pragma unroll
        for (int e = 0; e < 8; ++e) Hg[e] = acc[e] + bvec[e];

        int a1 = 0;
#pragma unroll
        for (int e = 1; e < 8; ++e) if (Hg[e] > Hg[a1]) a1 = e;
        float m1 = Hg[a1];
        float m2 = -1e30f;
#pragma unroll
        for (int e = 0; e < 8; ++e) if (e != a1 && Hg[e] > m2) m2 = Hg[e];

        float ex[8]; float sum = 0.f;
#pragma unroll
        for (int e = 0; e < 8; ++e) { ex[e] = expf(Hg[e] - m1); sum += ex[e]; }
        float inv = 1.f / sum;
#pragma unroll
        for (int e = 0; e < 8; ++e)
            probs_out[(size_t)t * 8 + e] = ex[e] * inv;

        float den = 0.f;
#pragma unroll
        for (int e = 0; e < 8; ++e) if (Hg[e] >= m2) den += ex[e];
        float invd = 1.f / den;
        int n = 0;
#pragma unroll
        for (int e = 0; e < 8; ++e) {
            if (Hg[e] >= m2) {
                sel_e[t * 8 + n] = e;
                sel_g[t * 8 + n] = ex[e] * invd;
                ++n;
                atomicAdd(&counts[e], 1);
            }
        }
        sel_cnt[t] = n;
    }
}

// ---------------------------------------------------------------------------
// Kernel 2: exclusive scan of 8 expert counts.
// ---------------------------------------------------------------------------
__global__ void scan_kernel(const int* __restrict__ counts, int* __restrict__ offsets)
{
    if (threadIdx.x == 0) {
        int tot = 0;
#pragma unroll
        for (int e = 0; e < 8; ++e) { offsets[e] = tot; tot += counts[e]; }
    }
}

// ---------------------------------------------------------------------------
// Kernel 3: scatter tokens into per-expert compacted pair lists.
// ---------------------------------------------------------------------------
__global__ __launch_bounds__(256) void scatter_kernel(
    const int* __restrict__ sel_cnt,
    const int* __restrict__ sel_e,
    const float* __restrict__ sel_g,
    const int* __restrict__ offsets,
    int* __restrict__ cursors,
    int* __restrict__ pair_token,
    float* __restrict__ pair_gate)
{
    int t = blockIdx.x * blockDim.x + threadIdx.x;
    if (t >= NTOK) return;
    int n = sel_cnt[t];
    for (int i = 0; i < n && i < 8; ++i) {
        int e = sel_e[t * 8 + i];
        int r = atomicAdd(&cursors[e], 1);
        int slot = offsets[e] + r;
        if (slot < CAP) {
            pair_token[slot] = t;
            pair_gate[slot]  = sel_g[t * 8 + i];
        }
    }
}

// ---------------------------------------------------------------------------
// Kernel 4: fc1 grouped GEMM (all-bf16 inputs).
// 128x128 tile, BK=64, global_load_lds(16B), G21 XOR-swizzle,
// T3 minimal 2-phase double-buffer: prefetch next K-tile under current MFMA;
// one raw s_barrier + counted vmcnt(0) per tile (no pre-compute drain).
// h[slot] = relu(x_bf[tok] @ fc1_wb[e]^T + fc1_b[e])  (bf16 out)
// ---------------------------------------------------------------------------
__global__ __launch_bounds__(256) void fc1_kernel(
    const unsigned short* __restrict__ xs_bf,
    const unsigned short* __restrict__ fc1_wb,
    const float* __restrict__ fc1_b,
    const int* __restrict__ counts,
    const int* __restrict__ offsets,
    const int* __restrict__ pair_token,
    unsigned short* __restrict__ h)
{
    const int e = blockIdx.z;
    const int cnt = counts[e];
    const int mtile = blockIdx.y;
    if (mtile * 128 >= cnt) return;
    const int ntile = blockIdx.x;
    const int offs = offsets[e];

    __shared__ __align__(16) unsigned short As[2][128 * 64];
    __shared__ __align__(16) unsigned short Bs[2][128 * 64];

    const int tid  = threadIdx.x;
    const int lane = tid & 63;
    const int wave = tid >> 6;
    const int wr = wave >> 1, wc = wave & 1;
    const int lrow = lane & 15;
    const int kq   = lane >> 4;

    const unsigned short* aSrc[4];
    const unsigned short* bSrc[4];
    int dstOff[4];
#pragma unroll
    for (int i = 0; i < 4; ++i) {
        int c = i * 256 + tid;          // 0..1023
        int row = c >> 3;
        int gran = (c & 7) ^ (row & 7); // G21 pre-swizzled source
        int m = mtile * 128 + row;
        int mc = m < cnt ? m : cnt - 1;
        int tok = pair_token[offs + mc];
        aSrc[i] = xs_bf + (size_t)tok * D_DIM + gran * 8;
        int n = ntile * 128 + row;
        bSrc[i] = fc1_wb + ((size_t)e * H_DIM + n) * D_DIM + gran * 8;
        dstOff[i] = (i * 256 + wave * 64) * 8;   // wave-uniform, linear
    }

    f32x4 acc[4][4];
#pragma unroll
    for (int i = 0; i < 4; ++i)
#pragma unroll
        for (int j = 0; j < 4; ++j)
            acc[i][j] = (f32x4){0.f, 0.f, 0.f, 0.f};

    auto stage = [&](int buf, int k0) {
#pragma unroll
        for (int i = 0; i < 4; ++i) {
            glds16(aSrc[i] + k0, &As[buf][dstOff[i]]);
            glds16(bSrc[i] + k0, &Bs[buf][dstOff[i]]);
        }
    };
    auto compute = [&](int buf) {
#pragma unroll
        for (int ks = 0; ks < 2; ++ks) {
            bf16x8 af[4], bfr[4];
            const int gr = ks * 4 + kq;
            const int sg = (gr ^ (lrow & 7)) * 8;
#pragma unroll
            for (int i = 0; i < 4; ++i) {
                af[i]  = *(const bf16x8*)&As[buf][(wr * 64 + i * 16 + lrow) * 64 + sg];
                bfr[i] = *(const bf16x8*)&Bs[buf][(wc * 64 + i * 16 + lrow) * 64 + sg];
            }
#pragma unroll
            for (int i = 0; i < 4; ++i)
#pragma unroll
                for (int j = 0; j < 4; ++j)
                    acc[i][j] = __builtin_amdgcn_mfma_f32_16x16x32_bf16(af[i], bfr[j], acc[i][j], 0, 0, 0);
        }
    };

    const int NT = D_DIM / 64;
    stage(0, 0);
    asm volatile("s_waitcnt vmcnt(0)" ::: "memory");
    __builtin_amdgcn_s_barrier();
    int cur = 0;
    for (int t = 0; t < NT - 1; ++t) {
        stage(cur ^ 1, (t + 1) * 64);   // prefetch overlaps compute below
        compute(cur);
        asm volatile("s_waitcnt vmcnt(0)" ::: "memory");
        __builtin_amdgcn_s_barrier();
        cur ^= 1;
    }
    compute(cur);

    int ncol[4]; float bias[4];
#pragma unroll
    for (int j = 0; j < 4; ++j) {
        ncol[j] = ntile * 128 + wc * 64 + j * 16 + lrow;
        bias[j] = fc1_b[e * H_DIM + ncol[j]];
    }
#pragma unroll
    for (int i = 0; i < 4; ++i) {
#pragma unroll
        for (int r = 0; r < 4; ++r) {
            int m = mtile * 128 + wr * 64 + i * 16 + kq * 4 + r;
            if (m < cnt) {
                size_t base = (size_t)(offs + m) * H_DIM;
#pragma unroll
                for (int j = 0; j < 4; ++j) {
                    float v = acc[i][j][r] + bias[j];
                    h[base + ncol[j]] = f2bf(v > 0.f ? v : 0.f);
                }
            }
        }
    }
}

// ---------------------------------------------------------------------------
// Kernel 5: fc2 grouped GEMM + gated accumulate into combined (fp32 atomics).
// Same 2-phase dbuf structure as fc1; A = h (bf16), B = fc2_wb (bf16).
// ---------------------------------------------------------------------------
__global__ __launch_bounds__(256) void fc2_kernel(
    const unsigned short* __restrict__ h,
    const unsigned short* __restrict__ fc2_wb,
    const float* __restrict__ fc2_b,
    const int* __restrict__ counts,
    const int* __restrict__ offsets,
    const int* __restrict__ pair_token,
    const float* __restrict__ pair_gate,
    float* __restrict__ combined)
{
    const int e = blockIdx.z;
    const int cnt = counts[e];
    const int mtile = blockIdx.y;
    if (mtile * 128 >= cnt) return;
    const int ntile = blockIdx.x;
    const int offs = offsets[e];

    __shared__ __align__(16) unsigned short As[2][128 * 64];
    __shared__ __align__(16) unsigned short Bs[2][128 * 64];

    const int tid  = threadIdx.x;
    const int lane = tid & 63;
    const int wave = tid >> 6;
    const int wr = wave >> 1, wc = wave & 1;
    const int lrow = lane & 15;
    const int kq   = lane >> 4;

    const unsigned short* aSrc[4];
    const unsigned short* bSrc[4];
    int dstOff[4];
#pragma unroll
    for (int i = 0; i < 4; ++i) {
        int c = i * 256 + tid;
        int row = c >> 3;
        int gran = (c & 7) ^ (row & 7);
        int m = mtile * 128 + row;
        int mc = m < cnt ? m : cnt - 1;
        aSrc[i] = h + (size_t)(offs + mc) * H_DIM + gran * 8;
        int n = ntile * 128 + row;
        bSrc[i] = fc2_wb + ((size_t)e * H_DIM + n) * H_DIM + gran * 8;
        dstOff[i] = (i * 256 + wave * 64) * 8;
    }

    f32x4 acc[4][4];
#pragma unroll
    for (int i = 0; i < 4; ++i)
#pragma unroll
        for (int j = 0; j < 4; ++j)
            acc[i][j] = (f32x4){0.f, 0.f, 0.f, 0.f};

    auto stage = [&](int buf, int k0) {
#pragma unroll
        for (int i = 0; i < 4; ++i) {
            glds16(aSrc[i] + k0, &As[buf][dstOff[i]]);
            glds16(bSrc[i] + k0, &Bs[buf][dstOff[i]]);
        }
    };
    auto compute = [&](int buf) {
#pragma unroll
        for (int ks = 0; ks < 2; ++ks) {
            bf16x8 af[4], bfr[4];
            const int gr = ks * 4 + kq;
            const int sg = (gr ^ (lrow & 7)) * 8;
#pragma unroll
            for (int i = 0; i < 4; ++i) {
                af[i]  = *(const bf16x8*)&As[buf][(wr * 64 + i * 16 + lrow) * 64 + sg];
                bfr[i] = *(const bf16x8*)&Bs[buf][(wc * 64 + i * 16 + lrow) * 64 + sg];
            }
#pragma unroll
            for (int i = 0; i < 4; ++i)
#pragma unroll
                for (int j = 0; j < 4; ++j)
                    acc[i][j] = __builtin_amdgcn_mfma_f32_16x16x32_bf16(af[i], bfr[j], acc[i][j], 0, 0, 0);
        }
    };

    const int NT = H_DIM / 64;
    stage(0, 0);
    asm volatile("s_waitcnt vmcnt(0)" ::: "memory");
    __builtin_amdgcn_s_barrier();
    int cur = 0;
    for (int t = 0; t < NT - 1; ++t) {
        stage(cur ^ 1, (t + 1) * 64);
        compute(cur);
        asm volatile("s_waitcnt vmcnt(0)" ::: "memory");
        __builtin_amdgcn_s_barrier();
        cur ^= 1;
    }
    compute(cur);

    int ncol[4]; float bias[4];
#pragma unroll
    for (int j = 0; j < 4; ++j) {
        ncol[j] = ntile * 128 + wc * 64 + j * 16 + lrow;
        bias[j] = fc2_b[e * H_DIM + ncol[j]];
    }
#pragma unroll
    for (int i = 0; i < 4; ++i) {
#pragma unroll
        for (int r = 0; r < 4; ++r) {
            int m = mtile * 128 + wr * 64 + i * 16 + kq * 4 + r;
            if (m < cnt) {
                int slot = offs + m;
                int tok  = pair_token[slot];
                float g  = pair_gate[slot] * 0.5f;   // 1/S
                int brow = tok & (B_DIM - 1);
#pragma unroll
                for (int j = 0; j < 4; ++j) {
                    float v = (acc[i][j][r] + bias[j]) * g;
                    atomicAdd(&combined[(size_t)brow * H_DIM + ncol[j]], v);
                }
            }
        }
    }
}

// ---------------------------------------------------------------------------
// Kernel 6: final GEMM, all-bf16 via pre-converted operands, same dbuf template.
// out = combined_bf @ final_wb^T + final_b (fp32 out). Rounding identical to
// the old stage8 path (f2bf applied to same fp32 values).
// ---------------------------------------------------------------------------
__global__ __launch_bounds__(256) void final_kernel(
    const unsigned short* __restrict__ combined_bf,
    const unsigned short* __restrict__ final_wb,
    const float* __restrict__ final_b,
    float* __restrict__ out)
{
    const int mtile = blockIdx.y;
    const int ntile = blockIdx.x;

    __shared__ __align__(16) unsigned short As[2][128 * 64];
    __shared__ __align__(16) unsigned short Bs[2][128 * 64];

    const int tid  = threadIdx.x;
    const int lane = tid & 63;
    const int wave = tid >> 6;
    const int wr = wave >> 1, wc = wave & 1;
    const int lrow = lane & 15;
    const int kq   = lane >> 4;

    const unsigned short* aSrc[4];
    const unsigned short* bSrc[4];
    int dstOff[4];
#pragma unroll
    for (int i = 0; i < 4; ++i) {
        int c = i * 256 + tid;
        int row = c >> 3;
        int gran = (c & 7) ^ (row & 7);
        int m = mtile * 128 + row;
        aSrc[i] = combined_bf + (size_t)m * H_DIM + gran * 8;
        int n = ntile * 128 + row;
        bSrc[i] = final_wb + (size_t)n * H_DIM + gran * 8;
        dstOff[i] = (i * 256 + wave * 64) * 8;
    }

    f32x4 acc[4][4];
#pragma unroll
    for (int i = 0; i < 4; ++i)
#pragma unroll
        for (int j = 0; j < 4; ++j)
            acc[i][j] = (f32x4){0.f, 0.f, 0.f, 0.f};

    auto stage = [&](int buf, int k0) {
#pragma unroll
        for (int i = 0; i < 4; ++i) {
            glds16(aSrc[i] + k0, &As[buf][dstOff[i]]);
            glds16(bSrc[i] + k0, &Bs[buf][dstOff[i]]);
        }
    };
    auto compute = [&](int buf) {
#pragma unroll
        for (int ks = 0; ks < 2; ++ks) {
            bf16x8 af[4], bfr[4];
            const int gr = ks * 4 + kq;
            const int sg = (gr ^ (lrow & 7)) * 8;
#pragma unroll
            for (int i = 0; i < 4; ++i) {
                af[i]  = *(const bf16x8*)&As[buf][(wr * 64 + i * 16 + lrow) * 64 + sg];
                bfr[i] = *(const bf16x8*)&Bs[buf][(wc * 64 + i * 16 + lrow) * 64 + sg];
            }
#pragma unroll
            for (int i = 0; i < 4; ++i)
#pragma unroll
                for (int j = 0; j < 4; ++j)
                    acc[i][j] = __builtin_amdgcn_mfma_f32_16x16x32_bf16(af[i], bfr[j], acc[i][j], 0, 0, 0);
        }
    };

    const int NT = H_DIM / 64;
    stage(0, 0);
    asm volatile("s_waitcnt vmcnt(0)" ::: "memory");
    __builtin_amdgcn_s_barrier();
    int cur = 0;
    for (int t = 0; t < NT - 1; ++t) {
        stage(cur ^ 1, (t + 1) * 64);
        compute(cur);
        asm volatile("s_waitcnt vmcnt(0)" ::: "memory");
        __builtin_amdgcn_s_barrier();
        cur ^= 1;
    }
    compute(cur);

    int ncol[4]; float bias[4];
#pragma unroll
    for (int j = 0; j < 4; ++j) {
        ncol[j] = ntile * 128 + wc * 64 + j * 16 + lrow;
        bias[j] = final_b[ncol[j]];
    }
#pragma unroll
    for (int i = 0; i < 4; ++i) {
#pragma unroll
        for (int r = 0; r < 4; ++r) {
            int m = mtile * 128 + wr * 64 + i * 16 + kq * 4 + r;
#pragma unroll
            for (int j = 0; j < 4; ++j)
                out[(size_t)m * O_DIM + ncol[j]] = acc[i][j][r] + bias[j];
        }
    }
}

// ---------------------------------------------------------------------------
extern "C" void kernel_launch(void* const* d_in, const int* in_sizes, int n_in,
                              void* d_out, int out_size, void* d_ws, size_t ws_size,
                              hipStream_t stream) {
    const float* xs      = (const float*)d_in[0];
    const float* Wg      = (const float*)d_in[1];
    const float* bvec    = (const float*)d_in[2];
    const float* fc1_w   = (const float*)d_in[3];
    const float* fc1_b   = (const float*)d_in[4];
    const float* fc2_w   = (const float*)d_in[5];
    const float* fc2_b   = (const float*)d_in[6];
    const float* final_w = (const float*)d_in[7];
    const float* final_b = (const float*)d_in[8];

    float* out = (float*)d_out;
    float* probs_out = out + (size_t)B_DIM * O_DIM;

    uint8_t* w = (uint8_t*)d_ws;
    int*   counts     = (int*)(w + 0);
    int*   cursors    = (int*)(w + 64);
    int*   offsets    = (int*)(w + 128);
    int*   sel_cnt    = (int*)(w + 256);        // 16 KB
    int*   sel_e      = (int*)(w + 0x5000);     // 128 KB
    float* sel_g      = (float*)(w + 0x25000);  // 128 KB
    int*   pair_token = (int*)(w + 0x45000);    // 48 KB
    float* pair_gate  = (float*)(w + 0x51000);  // 48 KB
    float* combined   = (float*)(w + 0x60000);  // 16 MB fp32
    unsigned short* h = (unsigned short*)(w + 0x1060000);       // 48 MB -> 0x4060000
    unsigned short* xs_bf   = (unsigned short*)(w + 0x4060000); // 8 MB  -> 0x4860000
    unsigned short* fc1_wb  = (unsigned short*)(w + 0x4860000); // 32 MB -> 0x6860000
    unsigned short* fc2_wb  = (unsigned short*)(w + 0x6860000); // 64 MB -> 0xA860000
    unsigned short* final_wb    = (unsigned short*)(w + 0xA860000); // 4 MB -> 0xAC60000
    unsigned short* combined_bf = (unsigned short*)(w + 0xAC60000); // 8 MB -> 0xB460000

    hipMemsetAsync(w, 0, 256, stream);
    hipMemsetAsync(combined, 0, (size_t)B_DIM * H_DIM * sizeof(float), stream);

    // weight fp32 -> bf16 (once per launch)
    convert_kernel<<<(E_DIM * H_DIM * D_DIM / 8) / 256, 256, 0, stream>>>(
        fc1_w, fc1_wb, E_DIM * H_DIM * D_DIM / 8);
    convert_kernel<<<(E_DIM * H_DIM * H_DIM / 8) / 256, 256, 0, stream>>>(
        fc2_w, fc2_wb, E_DIM * H_DIM * H_DIM / 8);
    convert_kernel<<<(O_DIM * H_DIM / 8) / 256, 256, 0, stream>>>(
        final_w, final_wb, O_DIM * H_DIM / 8);

    gating_kernel<<<NTOK / 4, 256, 0, stream>>>(xs, Wg, bvec, probs_out,
                                                counts, sel_cnt, sel_e, sel_g, xs_bf);
    scan_kernel<<<1, 64, 0, stream>>>(counts, offsets);
    scatter_kernel<<<NTOK / 256, 256, 0, stream>>>(sel_cnt, sel_e, sel_g, offsets,
                                                   cursors, pair_token, pair_gate);
    fc1_kernel<<<dim3(H_DIM / 128, NTOK / 128, E_DIM), 256, 0, stream>>>(
        xs_bf, fc1_wb, fc1_b, counts, offsets, pair_token, h);
    fc2_kernel<<<dim3(H_DIM / 128, NTOK / 128, E_DIM), 256, 0, stream>>>(
        h, fc2_wb, fc2_b, counts, offsets, pair_token, pair_gate, combined);
    convert_kernel<<<(B_DIM * H_DIM / 8) / 256, 256, 0, stream>>>(
        combined, combined_bf, B_DIM * H_DIM / 8);
    final_kernel<<<dim3(O_DIM / 128, B_DIM / 128), 256, 0, stream>>>(
        combined_bf, final_wb, final_b, out);
}

// Round 4
// 662.509 us; speedup vs baseline: 1.1027x; 1.1027x over previous
//
#include <hip/hip_runtime.h>
#include <stdint.h>

#define S_DIM 2
#define B_DIM 2048
#define D_DIM 1024
#define H_DIM 2048
#define E_DIM 8
#define O_DIM 1024
#define NTOK 4096            // S*B
#define CAP 12288            // pair capacity (normal total = 8192)

typedef __attribute__((ext_vector_type(8))) short bf16x8;
typedef __attribute__((ext_vector_type(4))) float f32x4;

__device__ __forceinline__ unsigned short f2bf(float f) {
    union { float f; uint32_t i; } c; c.f = f;
    uint32_t r = c.i + 0x7FFFu + ((c.i >> 16) & 1u);
    return (unsigned short)(r >> 16);
}
__device__ __forceinline__ uint32_t pack2(float a, float b) {
    return (uint32_t)f2bf(a) | ((uint32_t)f2bf(b) << 16);
}
// read 8 fp32, round to bf16, write 16B
__device__ __forceinline__ void stage8(const float* __restrict__ src,
                                       unsigned short* __restrict__ dst) {
    float4 f0 = *(const float4*)src;
    float4 f1 = *(const float4*)(src + 4);
    int4 v;
    v.x = (int)pack2(f0.x, f0.y);
    v.y = (int)pack2(f0.z, f0.w);
    v.z = (int)pack2(f1.x, f1.y);
    v.w = (int)pack2(f1.z, f1.w);
    *(int4*)dst = v;
}

// async global(16B)->LDS. Global addr is per-lane; LDS dest must be wave-uniform
// (HW adds lane*16).
__device__ __forceinline__ void glds16(const unsigned short* g, unsigned short* l) {
    __builtin_amdgcn_global_load_lds(
        (__attribute__((address_space(1))) void*)g,
        (__attribute__((address_space(3))) void*)l,
        16, 0, 0);
}

// ---------------------------------------------------------------------------
// Kernel 0: fp32 -> bf16 bulk convert. 8 elems / thread.
// ---------------------------------------------------------------------------
__global__ __launch_bounds__(256) void convert_kernel(
    const float* __restrict__ src, unsigned short* __restrict__ dst, int n8)
{
    int i = blockIdx.x * blockDim.x + threadIdx.x;
    if (i < n8) stage8(src + (size_t)i * 8, dst + (size_t)i * 8);
}

// ---------------------------------------------------------------------------
// Kernel 1: gating (pure fp32 — must reproduce reference top-2 selection).
// One wave per token. Also emits xs in bf16 (it reads all of xs anyway).
// ---------------------------------------------------------------------------
__global__ __launch_bounds__(256) void gating_kernel(
    const float* __restrict__ xs,
    const float* __restrict__ Wg,
    const float* __restrict__ bvec,
    float* __restrict__ probs_out,
    int* __restrict__ counts,
    int* __restrict__ sel_cnt,
    int* __restrict__ sel_e,
    float* __restrict__ sel_g,
    unsigned short* __restrict__ xs_bf)
{
    const int wave = threadIdx.x >> 6;
    const int lane = threadIdx.x & 63;
    const int t = blockIdx.x * 4 + wave;
    const float* x = xs + (size_t)t * D_DIM;

    float acc[8];
#pragma unroll
    for (int e = 0; e < 8; ++e) acc[e] = 0.f;

#pragma unroll
    for (int i = 0; i < D_DIM / 64; ++i) {
        int d = i * 64 + lane;
        float xv = x[d];
        xs_bf[(size_t)t * D_DIM + d] = f2bf(xv);
        float4 w0 = *(const float4*)(Wg + (size_t)d * 8);
        float4 w1 = *(const float4*)(Wg + (size_t)d * 8 + 4);
        acc[0] += xv * w0.x; acc[1] += xv * w0.y;
        acc[2] += xv * w0.z; acc[3] += xv * w0.w;
        acc[4] += xv * w1.x; acc[5] += xv * w1.y;
        acc[6] += xv * w1.z; acc[7] += xv * w1.w;
    }
#pragma unroll
    for (int off = 32; off > 0; off >>= 1) {
#pragma unroll
        for (int e = 0; e < 8; ++e)
            acc[e] += __shfl_down(acc[e], off);
    }

    if (lane == 0) {
        float Hg[8];
#pragma unroll
        for (int e = 0; e < 8; ++e) Hg[e] = acc[e] + bvec[e];

        int a1 = 0;
#pragma unroll
        for (int e = 1; e < 8; ++e) if (Hg[e] > Hg[a1]) a1 = e;
        float m1 = Hg[a1];
        float m2 = -1e30f;
#pragma unroll
        for (int e = 0; e < 8; ++e) if (e != a1 && Hg[e] > m2) m2 = Hg[e];

        float ex[8]; float sum = 0.f;
#pragma unroll
        for (int e = 0; e < 8; ++e) { ex[e] = expf(Hg[e] - m1); sum += ex[e]; }
        float inv = 1.f / sum;
#pragma unroll
        for (int e = 0; e < 8; ++e)
            probs_out[(size_t)t * 8 + e] = ex[e] * inv;

        float den = 0.f;
#pragma unroll
        for (int e = 0; e < 8; ++e) if (Hg[e] >= m2) den += ex[e];
        float invd = 1.f / den;
        int n = 0;
#pragma unroll
        for (int e = 0; e < 8; ++e) {
            if (Hg[e] >= m2) {
                sel_e[t * 8 + n] = e;
                sel_g[t * 8 + n] = ex[e] * invd;
                ++n;
                atomicAdd(&counts[e], 1);
            }
        }
        sel_cnt[t] = n;
    }
}

// ---------------------------------------------------------------------------
// Kernel 2: exclusive scan of 8 expert counts.
// ---------------------------------------------------------------------------
__global__ void scan_kernel(const int* __restrict__ counts, int* __restrict__ offsets)
{
    if (threadIdx.x == 0) {
        int tot = 0;
#pragma unroll
        for (int e = 0; e < 8; ++e) { offsets[e] = tot; tot += counts[e]; }
    }
}

// ---------------------------------------------------------------------------
// Kernel 3: scatter tokens into per-expert compacted pair lists.
// ---------------------------------------------------------------------------
__global__ __launch_bounds__(256) void scatter_kernel(
    const int* __restrict__ sel_cnt,
    const int* __restrict__ sel_e,
    const float* __restrict__ sel_g,
    const int* __restrict__ offsets,
    int* __restrict__ cursors,
    int* __restrict__ pair_token,
    float* __restrict__ pair_gate)
{
    int t = blockIdx.x * blockDim.x + threadIdx.x;
    if (t >= NTOK) return;
    int n = sel_cnt[t];
    for (int i = 0; i < n && i < 8; ++i) {
        int e = sel_e[t * 8 + i];
        int r = atomicAdd(&cursors[e], 1);
        int slot = offsets[e] + r;
        if (slot < CAP) {
            pair_token[slot] = t;
            pair_gate[slot]  = sel_g[t * 8 + i];
        }
    }
}

// ---------------------------------------------------------------------------
// Kernel 4: fc1 grouped GEMM (all-bf16). R2-proven single-buffer structure.
// 1D grid, expert = wgid&7 -> pins each expert's working set to one XCD's L2
// (blockIdx.x%8 round-robins XCDs). ntile fastest within expert for compact
// active-block runs.
// h[slot] = relu(x_bf[tok] @ fc1_wb[e]^T + fc1_b[e])  (bf16 out)
// ---------------------------------------------------------------------------
__global__ __launch_bounds__(256) void fc1_kernel(
    const unsigned short* __restrict__ xs_bf,
    const unsigned short* __restrict__ fc1_wb,
    const float* __restrict__ fc1_b,
    const int* __restrict__ counts,
    const int* __restrict__ offsets,
    const int* __restrict__ pair_token,
    unsigned short* __restrict__ h)
{
    const int wg = blockIdx.x;
    const int e = wg & 7;               // XCD pin
    const int idx = wg >> 3;
    const int mtile = idx >> 4;         // ntile fastest
    const int ntile = idx & 15;
    const int cnt = counts[e];
    if (mtile * 128 >= cnt) return;
    const int offs = offsets[e];

    __shared__ __align__(16) unsigned short As[128 * 64];
    __shared__ __align__(16) unsigned short Bs[128 * 64];

    const int tid  = threadIdx.x;
    const int lane = tid & 63;
    const int wave = tid >> 6;
    const int wr = wave >> 1, wc = wave & 1;
    const int lrow = lane & 15;
    const int kq   = lane >> 4;

    const unsigned short* aSrc[4];
    const unsigned short* bSrc[4];
    int dstOff[4];
#pragma unroll
    for (int i = 0; i < 4; ++i) {
        int c = i * 256 + tid;          // 0..1023
        int row = c >> 3;
        int gran = (c & 7) ^ (row & 7); // G21 pre-swizzled source
        int m = mtile * 128 + row;
        int mc = m < cnt ? m : cnt - 1;
        int tok = pair_token[offs + mc];
        aSrc[i] = xs_bf + (size_t)tok * D_DIM + gran * 8;
        int n = ntile * 128 + row;
        bSrc[i] = fc1_wb + ((size_t)e * H_DIM + n) * D_DIM + gran * 8;
        dstOff[i] = (i * 256 + wave * 64) * 8;   // wave-uniform, linear
    }

    f32x4 acc[4][4];
#pragma unroll
    for (int i = 0; i < 4; ++i)
#pragma unroll
        for (int j = 0; j < 4; ++j)
            acc[i][j] = (f32x4){0.f, 0.f, 0.f, 0.f};

    for (int k0 = 0; k0 < D_DIM; k0 += 64) {
        __syncthreads();
#pragma unroll
        for (int i = 0; i < 4; ++i) {
            glds16(aSrc[i] + k0, &As[dstOff[i]]);
            glds16(bSrc[i] + k0, &Bs[dstOff[i]]);
        }
        __syncthreads();
#pragma unroll
        for (int ks = 0; ks < 2; ++ks) {
            bf16x8 af[4], bfr[4];
            const int gr = ks * 4 + kq;
            const int sg = (gr ^ (lrow & 7)) * 8;
#pragma unroll
            for (int i = 0; i < 4; ++i) {
                af[i]  = *(const bf16x8*)&As[(wr * 64 + i * 16 + lrow) * 64 + sg];
                bfr[i] = *(const bf16x8*)&Bs[(wc * 64 + i * 16 + lrow) * 64 + sg];
            }
#pragma unroll
            for (int i = 0; i < 4; ++i)
#pragma unroll
                for (int j = 0; j < 4; ++j)
                    acc[i][j] = __builtin_amdgcn_mfma_f32_16x16x32_bf16(af[i], bfr[j], acc[i][j], 0, 0, 0);
        }
    }

    int ncol[4]; float bias[4];
#pragma unroll
    for (int j = 0; j < 4; ++j) {
        ncol[j] = ntile * 128 + wc * 64 + j * 16 + lrow;
        bias[j] = fc1_b[e * H_DIM + ncol[j]];
    }
#pragma unroll
    for (int i = 0; i < 4; ++i) {
#pragma unroll
        for (int r = 0; r < 4; ++r) {
            int m = mtile * 128 + wr * 64 + i * 16 + kq * 4 + r;
            if (m < cnt) {
                size_t base = (size_t)(offs + m) * H_DIM;
#pragma unroll
                for (int j = 0; j < 4; ++j) {
                    float v = acc[i][j][r] + bias[j];
                    h[base + ncol[j]] = f2bf(v > 0.f ? v : 0.f);
                }
            }
        }
    }
}

// ---------------------------------------------------------------------------
// Kernel 5: fc2 grouped GEMM + gated accumulate into combined (fp32 atomics).
// Same R2-proven structure + XCD expert pinning.
// ---------------------------------------------------------------------------
__global__ __launch_bounds__(256) void fc2_kernel(
    const unsigned short* __restrict__ h,
    const unsigned short* __restrict__ fc2_wb,
    const float* __restrict__ fc2_b,
    const int* __restrict__ counts,
    const int* __restrict__ offsets,
    const int* __restrict__ pair_token,
    const float* __restrict__ pair_gate,
    float* __restrict__ combined)
{
    const int wg = blockIdx.x;
    const int e = wg & 7;               // XCD pin
    const int idx = wg >> 3;
    const int mtile = idx >> 4;
    const int ntile = idx & 15;
    const int cnt = counts[e];
    if (mtile * 128 >= cnt) return;
    const int offs = offsets[e];

    __shared__ __align__(16) unsigned short As[128 * 64];
    __shared__ __align__(16) unsigned short Bs[128 * 64];

    const int tid  = threadIdx.x;
    const int lane = tid & 63;
    const int wave = tid >> 6;
    const int wr = wave >> 1, wc = wave & 1;
    const int lrow = lane & 15;
    const int kq   = lane >> 4;

    const unsigned short* aSrc[4];
    const unsigned short* bSrc[4];
    int dstOff[4];
#pragma unroll
    for (int i = 0; i < 4; ++i) {
        int c = i * 256 + tid;
        int row = c >> 3;
        int gran = (c & 7) ^ (row & 7);
        int m = mtile * 128 + row;
        int mc = m < cnt ? m : cnt - 1;
        aSrc[i] = h + (size_t)(offs + mc) * H_DIM + gran * 8;
        int n = ntile * 128 + row;
        bSrc[i] = fc2_wb + ((size_t)e * H_DIM + n) * H_DIM + gran * 8;
        dstOff[i] = (i * 256 + wave * 64) * 8;
    }

    f32x4 acc[4][4];
#pragma unroll
    for (int i = 0; i < 4; ++i)
#pragma unroll
        for (int j = 0; j < 4; ++j)
            acc[i][j] = (f32x4){0.f, 0.f, 0.f, 0.f};

    for (int k0 = 0; k0 < H_DIM; k0 += 64) {
        __syncthreads();
#pragma unroll
        for (int i = 0; i < 4; ++i) {
            glds16(aSrc[i] + k0, &As[dstOff[i]]);
            glds16(bSrc[i] + k0, &Bs[dstOff[i]]);
        }
        __syncthreads();
#pragma unroll
        for (int ks = 0; ks < 2; ++ks) {
            bf16x8 af[4], bfr[4];
            const int gr = ks * 4 + kq;
            const int sg = (gr ^ (lrow & 7)) * 8;
#pragma unroll
            for (int i = 0; i < 4; ++i) {
                af[i]  = *(const bf16x8*)&As[(wr * 64 + i * 16 + lrow) * 64 + sg];
                bfr[i] = *(const bf16x8*)&Bs[(wc * 64 + i * 16 + lrow) * 64 + sg];
            }
#pragma unroll
            for (int i = 0; i < 4; ++i)
#pragma unroll
                for (int j = 0; j < 4; ++j)
                    acc[i][j] = __builtin_amdgcn_mfma_f32_16x16x32_bf16(af[i], bfr[j], acc[i][j], 0, 0, 0);
        }
    }

    int ncol[4]; float bias[4];
#pragma unroll
    for (int j = 0; j < 4; ++j) {
        ncol[j] = ntile * 128 + wc * 64 + j * 16 + lrow;
        bias[j] = fc2_b[e * H_DIM + ncol[j]];
    }
#pragma unroll
    for (int i = 0; i < 4; ++i) {
#pragma unroll
        for (int r = 0; r < 4; ++r) {
            int m = mtile * 128 + wr * 64 + i * 16 + kq * 4 + r;
            if (m < cnt) {
                int slot = offs + m;
                int tok  = pair_token[slot];
                float g  = pair_gate[slot] * 0.5f;   // 1/S
                int brow = tok & (B_DIM - 1);
#pragma unroll
                for (int j = 0; j < 4; ++j) {
                    float v = (acc[i][j][r] + bias[j]) * g;
                    atomicAdd(&combined[(size_t)brow * H_DIM + ncol[j]], v);
                }
            }
        }
    }
}

// ---------------------------------------------------------------------------
// Kernel 6: final GEMM, all-bf16, single-buffer (dbuf reverted).
// out = combined_bf @ final_wb^T + final_b (fp32 out)
// ---------------------------------------------------------------------------
__global__ __launch_bounds__(256) void final_kernel(
    const unsigned short* __restrict__ combined_bf,
    const unsigned short* __restrict__ final_wb,
    const float* __restrict__ final_b,
    float* __restrict__ out)
{
    const int mtile = blockIdx.y;
    const int ntile = blockIdx.x;

    __shared__ __align__(16) unsigned short As[128 * 64];
    __shared__ __align__(16) unsigned short Bs[128 * 64];

    const int tid  = threadIdx.x;
    const int lane = tid & 63;
    const int wave = tid >> 6;
    const int wr = wave >> 1, wc = wave & 1;
    const int lrow = lane & 15;
    const int kq   = lane >> 4;

    const unsigned short* aSrc[4];
    const unsigned short* bSrc[4];
    int dstOff[4];
#pragma unroll
    for (int i = 0; i < 4; ++i) {
        int c = i * 256 + tid;
        int row = c >> 3;
        int gran = (c & 7) ^ (row & 7);
        int m = mtile * 128 + row;
        aSrc[i] = combined_bf + (size_t)m * H_DIM + gran * 8;
        int n = ntile * 128 + row;
        bSrc[i] = final_wb + (size_t)n * H_DIM + gran * 8;
        dstOff[i] = (i * 256 + wave * 64) * 8;
    }

    f32x4 acc[4][4];
#pragma unroll
    for (int i = 0; i < 4; ++i)
#pragma unroll
        for (int j = 0; j < 4; ++j)
            acc[i][j] = (f32x4){0.f, 0.f, 0.f, 0.f};

    for (int k0 = 0; k0 < H_DIM; k0 += 64) {
        __syncthreads();
#pragma unroll
        for (int i = 0; i < 4; ++i) {
            glds16(aSrc[i] + k0, &As[dstOff[i]]);
            glds16(bSrc[i] + k0, &Bs[dstOff[i]]);
        }
        __syncthreads();
#pragma unroll
        for (int ks = 0; ks < 2; ++ks) {
            bf16x8 af[4], bfr[4];
            const int gr = ks * 4 + kq;
            const int sg = (gr ^ (lrow & 7)) * 8;
#pragma unroll
            for (int i = 0; i < 4; ++i) {
                af[i]  = *(const bf16x8*)&As[(wr * 64 + i * 16 + lrow) * 64 + sg];
                bfr[i] = *(const bf16x8*)&Bs[(wc * 64 + i * 16 + lrow) * 64 + sg];
            }
#pragma unroll
            for (int i = 0; i < 4; ++i)
#pragma unroll
                for (int j = 0; j < 4; ++j)
                    acc[i][j] = __builtin_amdgcn_mfma_f32_16x16x32_bf16(af[i], bfr[j], acc[i][j], 0, 0, 0);
        }
    }

    int ncol[4]; float bias[4];
#pragma unroll
    for (int j = 0; j < 4; ++j) {
        ncol[j] = ntile * 128 + wc * 64 + j * 16 + lrow;
        bias[j] = final_b[ncol[j]];
    }
#pragma unroll
    for (int i = 0; i < 4; ++i) {
#pragma unroll
        for (int r = 0; r < 4; ++r) {
            int m = mtile * 128 + wr * 64 + i * 16 + kq * 4 + r;
#pragma unroll
            for (int j = 0; j < 4; ++j)
                out[(size_t)m * O_DIM + ncol[j]] = acc[i][j][r] + bias[j];
        }
    }
}

// ---------------------------------------------------------------------------
extern "C" void kernel_launch(void* const* d_in, const int* in_sizes, int n_in,
                              void* d_out, int out_size, void* d_ws, size_t ws_size,
                              hipStream_t stream) {
    const float* xs      = (const float*)d_in[0];
    const float* Wg      = (const float*)d_in[1];
    const float* bvec    = (const float*)d_in[2];
    const float* fc1_w   = (const float*)d_in[3];
    const float* fc1_b   = (const float*)d_in[4];
    const float* fc2_w   = (const float*)d_in[5];
    const float* fc2_b   = (const float*)d_in[6];
    const float* final_w = (const float*)d_in[7];
    const float* final_b = (const float*)d_in[8];

    float* out = (float*)d_out;
    float* probs_out = out + (size_t)B_DIM * O_DIM;

    uint8_t* w = (uint8_t*)d_ws;
    int*   counts     = (int*)(w + 0);
    int*   cursors    = (int*)(w + 64);
    int*   offsets    = (int*)(w + 128);
    int*   sel_cnt    = (int*)(w + 256);        // 16 KB
    int*   sel_e      = (int*)(w + 0x5000);     // 128 KB
    float* sel_g      = (float*)(w + 0x25000);  // 128 KB
    int*   pair_token = (int*)(w + 0x45000);    // 48 KB
    float* pair_gate  = (float*)(w + 0x51000);  // 48 KB
    float* combined   = (float*)(w + 0x60000);  // 16 MB fp32
    unsigned short* h = (unsigned short*)(w + 0x1060000);       // 48 MB -> 0x4060000
    unsigned short* xs_bf   = (unsigned short*)(w + 0x4060000); // 8 MB  -> 0x4860000
    unsigned short* fc1_wb  = (unsigned short*)(w + 0x4860000); // 32 MB -> 0x6860000
    unsigned short* fc2_wb  = (unsigned short*)(w + 0x6860000); // 64 MB -> 0xA860000
    unsigned short* final_wb    = (unsigned short*)(w + 0xA860000); // 4 MB -> 0xAC60000
    unsigned short* combined_bf = (unsigned short*)(w + 0xAC60000); // 8 MB -> 0xB460000

    hipMemsetAsync(w, 0, 256, stream);
    hipMemsetAsync(combined, 0, (size_t)B_DIM * H_DIM * sizeof(float), stream);

    // weight fp32 -> bf16 (once per launch)
    convert_kernel<<<(E_DIM * H_DIM * D_DIM / 8) / 256, 256, 0, stream>>>(
        fc1_w, fc1_wb, E_DIM * H_DIM * D_DIM / 8);
    convert_kernel<<<(E_DIM * H_DIM * H_DIM / 8) / 256, 256, 0, stream>>>(
        fc2_w, fc2_wb, E_DIM * H_DIM * H_DIM / 8);
    convert_kernel<<<(O_DIM * H_DIM / 8) / 256, 256, 0, stream>>>(
        final_w, final_wb, O_DIM * H_DIM / 8);

    gating_kernel<<<NTOK / 4, 256, 0, stream>>>(xs, Wg, bvec, probs_out,
                                                counts, sel_cnt, sel_e, sel_g, xs_bf);
    scan_kernel<<<1, 64, 0, stream>>>(counts, offsets);
    scatter_kernel<<<NTOK / 256, 256, 0, stream>>>(sel_cnt, sel_e, sel_g, offsets,
                                                   cursors, pair_token, pair_gate);
    // 1D grids: expert = wgid&7 (XCD pin), then mtile-major over idx>>3.
    fc1_kernel<<<E_DIM * (NTOK / 128) * (H_DIM / 128), 256, 0, stream>>>(
        xs_bf, fc1_wb, fc1_b, counts, offsets, pair_token, h);
    fc2_kernel<<<E_DIM * (NTOK / 128) * (H_DIM / 128), 256, 0, stream>>>(
        h, fc2_wb, fc2_b, counts, offsets, pair_token, pair_gate, combined);
    convert_kernel<<<(B_DIM * H_DIM / 8) / 256, 256, 0, stream>>>(
        combined, combined_bf, B_DIM * H_DIM / 8);
    final_kernel<<<dim3(O_DIM / 128, B_DIM / 128), 256, 0, stream>>>(
        combined_bf, final_wb, final_b, out);
}

// Round 5
// 625.891 us; speedup vs baseline: 1.1672x; 1.0585x over previous
//
#include <hip/hip_runtime.h>
#include <stdint.h>

#define S_DIM 2
#define B_DIM 2048
#define D_DIM 1024
#define H_DIM 2048
#define E_DIM 8
#define O_DIM 1024
#define NTOK 4096            // S*B
#define CAP 12288            // pair capacity (normal total = 8192)

typedef __attribute__((ext_vector_type(8))) short bf16x8;
typedef __attribute__((ext_vector_type(4))) float f32x4;

__device__ __forceinline__ unsigned short f2bf(float f) {
    union { float f; uint32_t i; } c; c.f = f;
    uint32_t r = c.i + 0x7FFFu + ((c.i >> 16) & 1u);
    return (unsigned short)(r >> 16);
}
__device__ __forceinline__ float bf2f(unsigned short u) {
    union { uint32_t i; float f; } c; c.i = (uint32_t)u << 16;
    return c.f;
}
__device__ __forceinline__ uint32_t pack2(float a, float b) {
    return (uint32_t)f2bf(a) | ((uint32_t)f2bf(b) << 16);
}
// read 8 fp32, round to bf16, write 16B
__device__ __forceinline__ void stage8(const float* __restrict__ src,
                                       unsigned short* __restrict__ dst) {
    float4 f0 = *(const float4*)src;
    float4 f1 = *(const float4*)(src + 4);
    int4 v;
    v.x = (int)pack2(f0.x, f0.y);
    v.y = (int)pack2(f0.z, f0.w);
    v.z = (int)pack2(f1.x, f1.y);
    v.w = (int)pack2(f1.z, f1.w);
    *(int4*)dst = v;
}

// async global(16B)->LDS. Global addr is per-lane; LDS dest must be wave-uniform
// (HW adds lane*16).
__device__ __forceinline__ void glds16(const unsigned short* g, unsigned short* l) {
    __builtin_amdgcn_global_load_lds(
        (__attribute__((address_space(1))) void*)g,
        (__attribute__((address_space(3))) void*)l,
        16, 0, 0);
}

// ---------------------------------------------------------------------------
// Kernel 0: fp32 -> bf16 bulk convert. 8 elems / thread.
// ---------------------------------------------------------------------------
__global__ __launch_bounds__(256) void convert_kernel(
    const float* __restrict__ src, unsigned short* __restrict__ dst, int n8)
{
    int i = blockIdx.x * blockDim.x + threadIdx.x;
    if (i < n8) stage8(src + (size_t)i * 8, dst + (size_t)i * 8);
}

// ---------------------------------------------------------------------------
// Kernel 1: gating (pure fp32 — must reproduce reference top-2 selection).
// One wave per token. Also emits xs in bf16 (it reads all of xs anyway).
// ---------------------------------------------------------------------------
__global__ __launch_bounds__(256) void gating_kernel(
    const float* __restrict__ xs,
    const float* __restrict__ Wg,
    const float* __restrict__ bvec,
    float* __restrict__ probs_out,
    int* __restrict__ counts,
    int* __restrict__ sel_cnt,
    int* __restrict__ sel_e,
    float* __restrict__ sel_g,
    unsigned short* __restrict__ xs_bf)
{
    const int wave = threadIdx.x >> 6;
    const int lane = threadIdx.x & 63;
    const int t = blockIdx.x * 4 + wave;
    const float* x = xs + (size_t)t * D_DIM;

    float acc[8];
#pragma unroll
    for (int e = 0; e < 8; ++e) acc[e] = 0.f;

#pragma unroll
    for (int i = 0; i < D_DIM / 64; ++i) {
        int d = i * 64 + lane;
        float xv = x[d];
        xs_bf[(size_t)t * D_DIM + d] = f2bf(xv);
        float4 w0 = *(const float4*)(Wg + (size_t)d * 8);
        float4 w1 = *(const float4*)(Wg + (size_t)d * 8 + 4);
        acc[0] += xv * w0.x; acc[1] += xv * w0.y;
        acc[2] += xv * w0.z; acc[3] += xv * w0.w;
        acc[4] += xv * w1.x; acc[5] += xv * w1.y;
        acc[6] += xv * w1.z; acc[7] += xv * w1.w;
    }
#pragma unroll
    for (int off = 32; off > 0; off >>= 1) {
#pragma unroll
        for (int e = 0; e < 8; ++e)
            acc[e] += __shfl_down(acc[e], off);
    }

    if (lane == 0) {
        float Hg[8];
#pragma unroll
        for (int e = 0; e < 8; ++e) Hg[e] = acc[e] + bvec[e];

        int a1 = 0;
#pragma unroll
        for (int e = 1; e < 8; ++e) if (Hg[e] > Hg[a1]) a1 = e;
        float m1 = Hg[a1];
        float m2 = -1e30f;
#pragma unroll
        for (int e = 0; e < 8; ++e) if (e != a1 && Hg[e] > m2) m2 = Hg[e];

        float ex[8]; float sum = 0.f;
#pragma unroll
        for (int e = 0; e < 8; ++e) { ex[e] = expf(Hg[e] - m1); sum += ex[e]; }
        float inv = 1.f / sum;
#pragma unroll
        for (int e = 0; e < 8; ++e)
            probs_out[(size_t)t * 8 + e] = ex[e] * inv;

        float den = 0.f;
#pragma unroll
        for (int e = 0; e < 8; ++e) if (Hg[e] >= m2) den += ex[e];
        float invd = 1.f / den;
        int n = 0;
#pragma unroll
        for (int e = 0; e < 8; ++e) {
            if (Hg[e] >= m2) {
                sel_e[t * 8 + n] = e;
                sel_g[t * 8 + n] = ex[e] * invd;
                ++n;
                atomicAdd(&counts[e], 1);
            }
        }
        sel_cnt[t] = n;
    }
}

// ---------------------------------------------------------------------------
// Kernel 2: exclusive scan of 8 expert counts.
// ---------------------------------------------------------------------------
__global__ void scan_kernel(const int* __restrict__ counts, int* __restrict__ offsets)
{
    if (threadIdx.x == 0) {
        int tot = 0;
#pragma unroll
        for (int e = 0; e < 8; ++e) { offsets[e] = tot; tot += counts[e]; }
    }
}

// ---------------------------------------------------------------------------
// Kernel 3: scatter tokens into per-expert compacted pair lists.
// Also records the inverse map token -> its slots (for the gather-reduce).
// ---------------------------------------------------------------------------
__global__ __launch_bounds__(256) void scatter_kernel(
    const int* __restrict__ sel_cnt,
    const int* __restrict__ sel_e,
    const float* __restrict__ sel_g,
    const int* __restrict__ offsets,
    int* __restrict__ cursors,
    int* __restrict__ pair_token,
    float* __restrict__ pair_gate,
    int* __restrict__ tok_slot)
{
    int t = blockIdx.x * blockDim.x + threadIdx.x;
    if (t >= NTOK) return;
    int n = sel_cnt[t];
    for (int i = 0; i < n && i < 8; ++i) {
        int e = sel_e[t * 8 + i];
        int r = atomicAdd(&cursors[e], 1);
        int slot = offsets[e] + r;
        if (slot < CAP) {
            pair_token[slot] = t;
            pair_gate[slot]  = sel_g[t * 8 + i];
            tok_slot[t * 8 + i] = slot;
        } else {
            tok_slot[t * 8 + i] = -1;
        }
    }
}

// ---------------------------------------------------------------------------
// Kernel 4: fc1 grouped GEMM (all-bf16). R2-proven single-buffer structure.
// 1D grid, expert = wgid&7 -> pins each expert's working set to one XCD's L2.
// h[slot] = relu(x_bf[tok] @ fc1_wb[e]^T + fc1_b[e])  (bf16 out)
// ---------------------------------------------------------------------------
__global__ __launch_bounds__(256) void fc1_kernel(
    const unsigned short* __restrict__ xs_bf,
    const unsigned short* __restrict__ fc1_wb,
    const float* __restrict__ fc1_b,
    const int* __restrict__ counts,
    const int* __restrict__ offsets,
    const int* __restrict__ pair_token,
    unsigned short* __restrict__ h)
{
    const int wg = blockIdx.x;
    const int e = wg & 7;               // XCD pin
    const int idx = wg >> 3;
    const int mtile = idx >> 4;         // ntile fastest
    const int ntile = idx & 15;
    const int cnt = counts[e];
    if (mtile * 128 >= cnt) return;
    const int offs = offsets[e];

    __shared__ __align__(16) unsigned short As[128 * 64];
    __shared__ __align__(16) unsigned short Bs[128 * 64];

    const int tid  = threadIdx.x;
    const int lane = tid & 63;
    const int wave = tid >> 6;
    const int wr = wave >> 1, wc = wave & 1;
    const int lrow = lane & 15;
    const int kq   = lane >> 4;

    const unsigned short* aSrc[4];
    const unsigned short* bSrc[4];
    int dstOff[4];
#pragma unroll
    for (int i = 0; i < 4; ++i) {
        int c = i * 256 + tid;          // 0..1023
        int row = c >> 3;
        int gran = (c & 7) ^ (row & 7); // G21 pre-swizzled source
        int m = mtile * 128 + row;
        int mc = m < cnt ? m : cnt - 1;
        int tok = pair_token[offs + mc];
        aSrc[i] = xs_bf + (size_t)tok * D_DIM + gran * 8;
        int n = ntile * 128 + row;
        bSrc[i] = fc1_wb + ((size_t)e * H_DIM + n) * D_DIM + gran * 8;
        dstOff[i] = (i * 256 + wave * 64) * 8;   // wave-uniform, linear
    }

    f32x4 acc[4][4];
#pragma unroll
    for (int i = 0; i < 4; ++i)
#pragma unroll
        for (int j = 0; j < 4; ++j)
            acc[i][j] = (f32x4){0.f, 0.f, 0.f, 0.f};

    for (int k0 = 0; k0 < D_DIM; k0 += 64) {
        __syncthreads();
#pragma unroll
        for (int i = 0; i < 4; ++i) {
            glds16(aSrc[i] + k0, &As[dstOff[i]]);
            glds16(bSrc[i] + k0, &Bs[dstOff[i]]);
        }
        __syncthreads();
#pragma unroll
        for (int ks = 0; ks < 2; ++ks) {
            bf16x8 af[4], bfr[4];
            const int gr = ks * 4 + kq;
            const int sg = (gr ^ (lrow & 7)) * 8;
#pragma unroll
            for (int i = 0; i < 4; ++i) {
                af[i]  = *(const bf16x8*)&As[(wr * 64 + i * 16 + lrow) * 64 + sg];
                bfr[i] = *(const bf16x8*)&Bs[(wc * 64 + i * 16 + lrow) * 64 + sg];
            }
#pragma unroll
            for (int i = 0; i < 4; ++i)
#pragma unroll
                for (int j = 0; j < 4; ++j)
                    acc[i][j] = __builtin_amdgcn_mfma_f32_16x16x32_bf16(af[i], bfr[j], acc[i][j], 0, 0, 0);
        }
    }

    int ncol[4]; float bias[4];
#pragma unroll
    for (int j = 0; j < 4; ++j) {
        ncol[j] = ntile * 128 + wc * 64 + j * 16 + lrow;
        bias[j] = fc1_b[e * H_DIM + ncol[j]];
    }
#pragma unroll
    for (int i = 0; i < 4; ++i) {
#pragma unroll
        for (int r = 0; r < 4; ++r) {
            int m = mtile * 128 + wr * 64 + i * 16 + kq * 4 + r;
            if (m < cnt) {
                size_t base = (size_t)(offs + m) * H_DIM;
#pragma unroll
                for (int j = 0; j < 4; ++j) {
                    float v = acc[i][j][r] + bias[j];
                    h[base + ncol[j]] = f2bf(v > 0.f ? v : 0.f);
                }
            }
        }
    }
}

// ---------------------------------------------------------------------------
// Kernel 5: fc2 grouped GEMM. Epilogue: PLAIN bf16 stores of pre-gated
// expert output eo_bf[slot] = (acc+bias)*g/S  (atomics removed — they were
// saturating L2 RMW service and stalling the whole kernel).
// ---------------------------------------------------------------------------
__global__ __launch_bounds__(256) void fc2_kernel(
    const unsigned short* __restrict__ h,
    const unsigned short* __restrict__ fc2_wb,
    const float* __restrict__ fc2_b,
    const int* __restrict__ counts,
    const int* __restrict__ offsets,
    const float* __restrict__ pair_gate,
    unsigned short* __restrict__ eo_bf)
{
    const int wg = blockIdx.x;
    const int e = wg & 7;               // XCD pin
    const int idx = wg >> 3;
    const int mtile = idx >> 4;
    const int ntile = idx & 15;
    const int cnt = counts[e];
    if (mtile * 128 >= cnt) return;
    const int offs = offsets[e];

    __shared__ __align__(16) unsigned short As[128 * 64];
    __shared__ __align__(16) unsigned short Bs[128 * 64];

    const int tid  = threadIdx.x;
    const int lane = tid & 63;
    const int wave = tid >> 6;
    const int wr = wave >> 1, wc = wave & 1;
    const int lrow = lane & 15;
    const int kq   = lane >> 4;

    const unsigned short* aSrc[4];
    const unsigned short* bSrc[4];
    int dstOff[4];
#pragma unroll
    for (int i = 0; i < 4; ++i) {
        int c = i * 256 + tid;
        int row = c >> 3;
        int gran = (c & 7) ^ (row & 7);
        int m = mtile * 128 + row;
        int mc = m < cnt ? m : cnt - 1;
        aSrc[i] = h + (size_t)(offs + mc) * H_DIM + gran * 8;
        int n = ntile * 128 + row;
        bSrc[i] = fc2_wb + ((size_t)e * H_DIM + n) * H_DIM + gran * 8;
        dstOff[i] = (i * 256 + wave * 64) * 8;
    }

    f32x4 acc[4][4];
#pragma unroll
    for (int i = 0; i < 4; ++i)
#pragma unroll
        for (int j = 0; j < 4; ++j)
            acc[i][j] = (f32x4){0.f, 0.f, 0.f, 0.f};

    for (int k0 = 0; k0 < H_DIM; k0 += 64) {
        __syncthreads();
#pragma unroll
        for (int i = 0; i < 4; ++i) {
            glds16(aSrc[i] + k0, &As[dstOff[i]]);
            glds16(bSrc[i] + k0, &Bs[dstOff[i]]);
        }
        __syncthreads();
#pragma unroll
        for (int ks = 0; ks < 2; ++ks) {
            bf16x8 af[4], bfr[4];
            const int gr = ks * 4 + kq;
            const int sg = (gr ^ (lrow & 7)) * 8;
#pragma unroll
            for (int i = 0; i < 4; ++i) {
                af[i]  = *(const bf16x8*)&As[(wr * 64 + i * 16 + lrow) * 64 + sg];
                bfr[i] = *(const bf16x8*)&Bs[(wc * 64 + i * 16 + lrow) * 64 + sg];
            }
#pragma unroll
            for (int i = 0; i < 4; ++i)
#pragma unroll
                for (int j = 0; j < 4; ++j)
                    acc[i][j] = __builtin_amdgcn_mfma_f32_16x16x32_bf16(af[i], bfr[j], acc[i][j], 0, 0, 0);
        }
    }

    int ncol[4]; float bias[4];
#pragma unroll
    for (int j = 0; j < 4; ++j) {
        ncol[j] = ntile * 128 + wc * 64 + j * 16 + lrow;
        bias[j] = fc2_b[e * H_DIM + ncol[j]];
    }
#pragma unroll
    for (int i = 0; i < 4; ++i) {
#pragma unroll
        for (int r = 0; r < 4; ++r) {
            int m = mtile * 128 + wr * 64 + i * 16 + kq * 4 + r;
            if (m < cnt) {
                int slot = offs + m;
                float g  = pair_gate[slot] * 0.5f;   // 1/S
                size_t base = (size_t)slot * H_DIM;
#pragma unroll
                for (int j = 0; j < 4; ++j) {
                    float v = (acc[i][j][r] + bias[j]) * g;
                    eo_bf[base + ncol[j]] = f2bf(v);
                }
            }
        }
    }
}

// ---------------------------------------------------------------------------
// Kernel 5b: gather-reduce. combined_bf[b][h] = sum over s,i of eo_bf[slot][h]
// (eo already pre-gated incl. 1/S). One block per batch row; coalesced rows.
// ---------------------------------------------------------------------------
__global__ __launch_bounds__(256) void reduce_kernel(
    const int* __restrict__ sel_cnt,
    const int* __restrict__ tok_slot,
    const unsigned short* __restrict__ eo_bf,
    unsigned short* __restrict__ combined_bf)
{
    const int b = blockIdx.x;
    const int h0 = threadIdx.x * 8;

    float acc[8];
#pragma unroll
    for (int j = 0; j < 8; ++j) acc[j] = 0.f;

#pragma unroll
    for (int s = 0; s < S_DIM; ++s) {
        int t = s * B_DIM + b;
        int n = sel_cnt[t];
        for (int i = 0; i < n && i < 8; ++i) {
            int slot = tok_slot[t * 8 + i];
            if (slot < 0) continue;
            bf16x8 v = *(const bf16x8*)&eo_bf[(size_t)slot * H_DIM + h0];
#pragma unroll
            for (int j = 0; j < 8; ++j)
                acc[j] += bf2f((unsigned short)v[j]);
        }
    }

    int4 o;
    o.x = (int)pack2(acc[0], acc[1]);
    o.y = (int)pack2(acc[2], acc[3]);
    o.z = (int)pack2(acc[4], acc[5]);
    o.w = (int)pack2(acc[6], acc[7]);
    *(int4*)&combined_bf[(size_t)b * H_DIM + h0] = o;
}

// ---------------------------------------------------------------------------
// Kernel 6: final GEMM, all-bf16, single-buffer.
// out = combined_bf @ final_wb^T + final_b (fp32 out)
// ---------------------------------------------------------------------------
__global__ __launch_bounds__(256) void final_kernel(
    const unsigned short* __restrict__ combined_bf,
    const unsigned short* __restrict__ final_wb,
    const float* __restrict__ final_b,
    float* __restrict__ out)
{
    const int mtile = blockIdx.y;
    const int ntile = blockIdx.x;

    __shared__ __align__(16) unsigned short As[128 * 64];
    __shared__ __align__(16) unsigned short Bs[128 * 64];

    const int tid  = threadIdx.x;
    const int lane = tid & 63;
    const int wave = tid >> 6;
    const int wr = wave >> 1, wc = wave & 1;
    const int lrow = lane & 15;
    const int kq   = lane >> 4;

    const unsigned short* aSrc[4];
    const unsigned short* bSrc[4];
    int dstOff[4];
#pragma unroll
    for (int i = 0; i < 4; ++i) {
        int c = i * 256 + tid;
        int row = c >> 3;
        int gran = (c & 7) ^ (row & 7);
        int m = mtile * 128 + row;
        aSrc[i] = combined_bf + (size_t)m * H_DIM + gran * 8;
        int n = ntile * 128 + row;
        bSrc[i] = final_wb + (size_t)n * H_DIM + gran * 8;
        dstOff[i] = (i * 256 + wave * 64) * 8;
    }

    f32x4 acc[4][4];
#pragma unroll
    for (int i = 0; i < 4; ++i)
#pragma unroll
        for (int j = 0; j < 4; ++j)
            acc[i][j] = (f32x4){0.f, 0.f, 0.f, 0.f};

    for (int k0 = 0; k0 < H_DIM; k0 += 64) {
        __syncthreads();
#pragma unroll
        for (int i = 0; i < 4; ++i) {
            glds16(aSrc[i] + k0, &As[dstOff[i]]);
            glds16(bSrc[i] + k0, &Bs[dstOff[i]]);
        }
        __syncthreads();
#pragma unroll
        for (int ks = 0; ks < 2; ++ks) {
            bf16x8 af[4], bfr[4];
            const int gr = ks * 4 + kq;
            const int sg = (gr ^ (lrow & 7)) * 8;
#pragma unroll
            for (int i = 0; i < 4; ++i) {
                af[i]  = *(const bf16x8*)&As[(wr * 64 + i * 16 + lrow) * 64 + sg];
                bfr[i] = *(const bf16x8*)&Bs[(wc * 64 + i * 16 + lrow) * 64 + sg];
            }
#pragma unroll
            for (int i = 0; i < 4; ++i)
#pragma unroll
                for (int j = 0; j < 4; ++j)
                    acc[i][j] = __builtin_amdgcn_mfma_f32_16x16x32_bf16(af[i], bfr[j], acc[i][j], 0, 0, 0);
        }
    }

    int ncol[4]; float bias[4];
#pragma unroll
    for (int j = 0; j < 4; ++j) {
        ncol[j] = ntile * 128 + wc * 64 + j * 16 + lrow;
        bias[j] = final_b[ncol[j]];
    }
#pragma unroll
    for (int i = 0; i < 4; ++i) {
#pragma unroll
        for (int r = 0; r < 4; ++r) {
            int m = mtile * 128 + wr * 64 + i * 16 + kq * 4 + r;
#pragma unroll
            for (int j = 0; j < 4; ++j)
                out[(size_t)m * O_DIM + ncol[j]] = acc[i][j][r] + bias[j];
        }
    }
}

// ---------------------------------------------------------------------------
extern "C" void kernel_launch(void* const* d_in, const int* in_sizes, int n_in,
                              void* d_out, int out_size, void* d_ws, size_t ws_size,
                              hipStream_t stream) {
    const float* xs      = (const float*)d_in[0];
    const float* Wg      = (const float*)d_in[1];
    const float* bvec    = (const float*)d_in[2];
    const float* fc1_w   = (const float*)d_in[3];
    const float* fc1_b   = (const float*)d_in[4];
    const float* fc2_w   = (const float*)d_in[5];
    const float* fc2_b   = (const float*)d_in[6];
    const float* final_w = (const float*)d_in[7];
    const float* final_b = (const float*)d_in[8];

    float* out = (float*)d_out;
    float* probs_out = out + (size_t)B_DIM * O_DIM;

    uint8_t* w = (uint8_t*)d_ws;
    int*   counts     = (int*)(w + 0);
    int*   cursors    = (int*)(w + 64);
    int*   offsets    = (int*)(w + 128);
    int*   sel_cnt    = (int*)(w + 256);        // 16 KB
    int*   sel_e      = (int*)(w + 0x5000);     // 128 KB
    float* sel_g      = (float*)(w + 0x25000);  // 128 KB
    int*   pair_token = (int*)(w + 0x45000);    // 48 KB
    float* pair_gate  = (float*)(w + 0x51000);  // 48 KB
    int*   tok_slot   = (int*)(w + 0x5D000);    // 128 KB -> 0x7D000
    unsigned short* h = (unsigned short*)(w + 0x1060000);       // 48 MB -> 0x4060000
    unsigned short* xs_bf   = (unsigned short*)(w + 0x4060000); // 8 MB  -> 0x4860000
    unsigned short* fc1_wb  = (unsigned short*)(w + 0x4860000); // 32 MB -> 0x6860000
    unsigned short* fc2_wb  = (unsigned short*)(w + 0x6860000); // 64 MB -> 0xA860000
    unsigned short* final_wb    = (unsigned short*)(w + 0xA860000); // 4 MB -> 0xAC60000
    unsigned short* combined_bf = (unsigned short*)(w + 0xAC60000); // 8 MB -> 0xB460000
    unsigned short* eo_bf       = (unsigned short*)(w + 0xB460000); // CAP*2048*2 = 48 MB -> 0xE460000

    hipMemsetAsync(w, 0, 256, stream);

    // weight fp32 -> bf16 (once per launch)
    convert_kernel<<<(E_DIM * H_DIM * D_DIM / 8) / 256, 256, 0, stream>>>(
        fc1_w, fc1_wb, E_DIM * H_DIM * D_DIM / 8);
    convert_kernel<<<(E_DIM * H_DIM * H_DIM / 8) / 256, 256, 0, stream>>>(
        fc2_w, fc2_wb, E_DIM * H_DIM * H_DIM / 8);
    convert_kernel<<<(O_DIM * H_DIM / 8) / 256, 256, 0, stream>>>(
        final_w, final_wb, O_DIM * H_DIM / 8);

    gating_kernel<<<NTOK / 4, 256, 0, stream>>>(xs, Wg, bvec, probs_out,
                                                counts, sel_cnt, sel_e, sel_g, xs_bf);
    scan_kernel<<<1, 64, 0, stream>>>(counts, offsets);
    scatter_kernel<<<NTOK / 256, 256, 0, stream>>>(sel_cnt, sel_e, sel_g, offsets,
                                                   cursors, pair_token, pair_gate,
                                                   tok_slot);
    // 1D grids: expert = wgid&7 (XCD pin), then ntile fastest within expert.
    fc1_kernel<<<E_DIM * (NTOK / 128) * (H_DIM / 128), 256, 0, stream>>>(
        xs_bf, fc1_wb, fc1_b, counts, offsets, pair_token, h);
    fc2_kernel<<<E_DIM * (NTOK / 128) * (H_DIM / 128), 256, 0, stream>>>(
        h, fc2_wb, fc2_b, counts, offsets, pair_gate, eo_bf);
    reduce_kernel<<<B_DIM, 256, 0, stream>>>(sel_cnt, tok_slot, eo_bf, combined_bf);
    final_kernel<<<dim3(O_DIM / 128, B_DIM / 128), 256, 0, stream>>>(
        combined_bf, final_wb, final_b, out);
}